// Round 3
// 7392.953 us; speedup vs baseline: 1.4900x; 1.4900x over previous
//
#include <hip/hip_runtime.h>

// VQ-VAE nearest centroid — bit-exact emulation of the reference fp32 pipeline.
// Model of the reference ("np"):
//   S[i,k]  = x.c^T element: single-accumulator ascending-k fp32 FMA chain
//             (what every BLAS microkernel emits: vfmadd231ps into one reg).
//   nx2/nc2 = PLAIN SEQUENTIAL ascending sum: r = fl(r + fl(v*v)), r0 = fl(v0*v0),
//             separate mul/add (no FMA) — XLA-CPU reduce / einsum / scalar-loop
//             order, NOT numpy pairwise (pairwise variants flipped row X twice).
//   dist    = fl( fl(-2*S + nx2) + nc2 );  argmin strict-< (first min).
//
// Layout: lane pair per row; even lane holds x[row][0:128] in VGPRs, odd holds
// x[row][128:256]. The ascending-d dot chain is software-pipelined across the
// pair via shfl_xor(1): evens compute HEADS (d 0..127) of cols 4g..4g+3 while
// odds continue TAILS (d 128..255) of cols 4(g-1).. from the received heads.
// Both parities run 512 FMAs/iter -> full VALU utilization with the exact
// single-chain order. __fmul_rn/__fadd_rn/fmaf pin the rounding everywhere.
//
// R1 FIX (rule #20 scratch demotion): the hot d-loop was `#pragma unroll 8`,
// leaving a[d] runtime-indexed -> the 128-VGPR x-row array lived in SCRATCH
// (VGPR_Count=60, FETCH_SIZE=16.5 GB scratch re-reads, VALUBusy=11%). Full
// `#pragma unroll` gives compile-time indices so the array stays in VGPRs.
// R3 SAFEGUARD: two consecutive "container failed" rounds on the R1 source.
// Suspected cause: with the inner loop fully unrolled, hipcc may also unroll
// the 257-trip OUTER loop (~800-inst body -> ~10^5 insts, compile blowup).
// `#pragma unroll 1` pins the outer loop. No change to operation order.

#define K_CENT 1024
#define DIM    256
#define RPB    128            // rows per block (256 threads, 2 lanes/row)

__device__ __forceinline__ float fmul(float a, float b) { return __fmul_rn(a, b); }
__device__ __forceinline__ float fadd(float a, float b) { return __fadd_rn(a, b); }

// ---- |c_k|^2: sequential ascending chain, one thread per centroid ----
__global__ __launch_bounds__(256)
void nc2_kernel(const float* __restrict__ c, float* __restrict__ nc2) {
    int k = blockIdx.x * blockDim.x + threadIdx.x;
    if (k >= K_CENT) return;
    const float* p = c + k * DIM;
    float r = 0.0f;
    #pragma unroll 1
    for (int d = 0; d < DIM; ++d) r = fadd(r, fmul(p[d], p[d]));
    nc2[k] = r;
}

__global__ __launch_bounds__(256, 2)
void vq_main(const float* __restrict__ x, const float* __restrict__ c,
             const float* __restrict__ nc2g, float* __restrict__ out) {
    const float4* __restrict__ x4 = (const float4*)x;
    const float4* __restrict__ c4 = (const float4*)c;
    float4* __restrict__ out4 = (float4*)out;

    __shared__ float cn2s[K_CENT];
    __shared__ int   bidx[RPB];

    const int t = threadIdx.x;
    for (int i = t; i < K_CENT; i += 256) cn2s[i] = nc2g[i];
    __syncthreads();

    const int rl       = t >> 1;          // local row 0..127
    const int half     = t & 1;           // 0: d[0,128)  1: d[128,256)
    const int rowsBase = blockIdx.x * RPB;
    const int row_g    = rowsBase + rl;

    // my half of the x row (32 float4 = 128 VGPRs)
    float4 a[32];
    {
        const float4* __restrict__ xp = x4 + (row_g << 6) + (half << 5);
        #pragma unroll
        for (int i = 0; i < 32; ++i) a[i] = xp[i];
    }

    // ---- nx2: sequential ascending chain across the lane pair.
    // Even lane chains d 0..127 from 0; odd lane continues d 128..255 from
    // the received partial. Only the odd lane's nx2 is ever consumed.
    float part = 0.0f;
    if (half == 0) {
        #pragma unroll
        for (int i = 0; i < 32; ++i) {
            part = fadd(part, fmul(a[i].x, a[i].x));
            part = fadd(part, fmul(a[i].y, a[i].y));
            part = fadd(part, fmul(a[i].z, a[i].z));
            part = fadd(part, fmul(a[i].w, a[i].w));
        }
    }
    float nx2 = __shfl_xor(part, 1, 64);  // odd lane: even's partial; even: 0
    if (half == 1) {
        #pragma unroll
        for (int i = 0; i < 32; ++i) {
            nx2 = fadd(nx2, fmul(a[i].x, a[i].x));
            nx2 = fadd(nx2, fmul(a[i].y, a[i].y));
            nx2 = fadd(nx2, fmul(a[i].z, a[i].z));
            nx2 = fadd(nx2, fmul(a[i].w, a[i].w));
        }
    }

    // ---- pipelined scan: evens do heads of group g, odds do tails of g-1.
    float h0 = 0.f, h1 = 0.f, h2 = 0.f, h3 = 0.f;
    float best = 3.4e38f;
    int   bi   = 0;
    const int hoff = half << 5;

    #pragma unroll 1
    for (int g = 0; g <= 256; ++g) {
        float s0 = __shfl_xor(h0, 1, 64);
        float s1 = __shfl_xor(h1, 1, 64);
        float s2 = __shfl_xor(h2, 1, 64);
        float s3 = __shfl_xor(h3, 1, 64);

        int colbase = (half ? (4 * (g - 1)) : (4 * g)) & (K_CENT - 1);
        const float4* __restrict__ cp0 = c4 + ((colbase + 0) << 6) + hoff;
        const float4* __restrict__ cp1 = c4 + ((colbase + 1) << 6) + hoff;
        const float4* __restrict__ cp2 = c4 + ((colbase + 2) << 6) + hoff;
        const float4* __restrict__ cp3 = c4 + ((colbase + 3) << 6) + hoff;

        float a0 = half ? s0 : 0.0f;      // odd: continue chain from head
        float a1 = half ? s1 : 0.0f;
        float a2 = half ? s2 : 0.0f;
        float a3 = half ? s3 : 0.0f;

        // FULL unroll: every a[d] index must be a compile-time constant so the
        // x-row stays in VGPRs (partial unroll demoted it to scratch — 16.5 GB
        // of HBM-visible scratch traffic, the R0 bottleneck).
        #pragma unroll
        for (int d = 0; d < 32; ++d) {
            float4 xv = a[d];
            float4 c0 = cp0[d], c1 = cp1[d], c2 = cp2[d], c3 = cp3[d];
            a0 = fmaf(xv.x, c0.x, a0); a0 = fmaf(xv.y, c0.y, a0);
            a0 = fmaf(xv.z, c0.z, a0); a0 = fmaf(xv.w, c0.w, a0);
            a1 = fmaf(xv.x, c1.x, a1); a1 = fmaf(xv.y, c1.y, a1);
            a1 = fmaf(xv.z, c1.z, a1); a1 = fmaf(xv.w, c1.w, a1);
            a2 = fmaf(xv.x, c2.x, a2); a2 = fmaf(xv.y, c2.y, a2);
            a2 = fmaf(xv.z, c2.z, a2); a2 = fmaf(xv.w, c2.w, a2);
            a3 = fmaf(xv.x, c3.x, a3); a3 = fmaf(xv.y, c3.y, a3);
            a3 = fmaf(xv.z, c3.z, a3); a3 = fmaf(xv.w, c3.w, a3);
        }

        h0 = a0; h1 = a1; h2 = a2; h3 = a3;

        if (g >= 1) {                      // odd lanes hold full dots for kbase..+3
            int kbase = 4 * (g - 1);
            float m0 = fadd(fadd(fmul(-2.0f, a0), nx2), cn2s[kbase + 0]);
            float m1 = fadd(fadd(fmul(-2.0f, a1), nx2), cn2s[kbase + 1]);
            float m2 = fadd(fadd(fmul(-2.0f, a2), nx2), cn2s[kbase + 2]);
            float m3 = fadd(fadd(fmul(-2.0f, a3), nx2), cn2s[kbase + 3]);
            if (m0 < best) { best = m0; bi = kbase + 0; }
            if (m1 < best) { best = m1; bi = kbase + 1; }
            if (m2 < best) { best = m2; bi = kbase + 2; }
            if (m3 < best) { best = m3; bi = kbase + 3; }
        }
    }

    if (half) bidx[rl] = bi;              // odd lane owns the row's answer
    __syncthreads();

    // ---- coalesced gather: out[rows] = c[bidx[row]] (bit-copies).
    #pragma unroll
    for (int k = 0; k < 32; ++k) {
        int L = t + (k << 8);
        int r = L >> 6, v = L & 63;
        out4[((rowsBase + r) << 6) + v] = c4[(bidx[r] << 6) + v];
    }
}

extern "C" void kernel_launch(void* const* d_in, const int* in_sizes, int n_in,
                              void* d_out, int out_size, void* d_ws, size_t ws_size,
                              hipStream_t stream) {
    const float* x = (const float*)d_in[0];
    const float* c = (const float*)d_in[1];
    float* out = (float*)d_out;
    float* nc2 = (float*)d_ws;           // 4 KiB scratch

    nc2_kernel<<<(K_CENT + 255) / 256, 256, 0, stream>>>(c, nc2);

    const int n_rows = in_sizes[0] / DIM;   // 131072
    vq_main<<<n_rows / RPB, 256, 0, stream>>>(x, c, nc2, out);
}